// Round 14
// baseline (167.679 us; speedup 1.0000x reference)
//
#include <hip/hip_runtime.h>
#include <hip/hip_bf16.h>
#include <math.h>

#define B 4
#define S 2048
#define H 4
#define DK 64
#define DM 256

using bf16x8 = __attribute__((ext_vector_type(8))) short;
using bf16x4 = __attribute__((ext_vector_type(4))) short;
using f32x4 = __attribute__((ext_vector_type(4))) float;
typedef unsigned char u8;

__device__ inline ushort f2b(float f) {
  __hip_bfloat16 h = __float2bfloat16(f);
  ushort u; __builtin_memcpy(&u, &h, 2); return u;
}
__device__ inline float b2f(ushort u) {
  __hip_bfloat16 h; __builtin_memcpy(&h, &u, 2); return __bfloat162float(h);
}
__device__ inline bf16x8 ld8(const ushort* p) {
  return *reinterpret_cast<const bf16x8*>(p);
}
__device__ inline bf16x4 ld4(const ushort* p) {
  return *reinterpret_cast<const bf16x4*>(p);
}
#define MFMA(a, b, c) __builtin_amdgcn_mfma_f32_16x16x32_bf16((a), (b), (c), 0, 0, 0)

#if __has_builtin(__builtin_amdgcn_mfma_f32_16x16x16bf16_1k)
__device__ inline f32x4 MFMA16(bf16x4 a, bf16x4 b, f32x4 c) {
  return __builtin_amdgcn_mfma_f32_16x16x16bf16_1k(a, b, c, 0, 0, 0);
}
#else
__device__ inline f32x4 MFMA16(bf16x4 a, bf16x4 b, f32x4 c) {
  asm("v_mfma_f32_16x16x16_bf16 %0, %1, %2, %0" : "+v"(c) : "v"(a), "v"(b));
  return c;
}
#endif

// LDS-only barrier: orders ds_write -> cross-wave ds_read WITHOUT draining
// the VMEM queue (vmcnt) — the NT attn-store stream retires asynchronously.
// __syncthreads would emit s_waitcnt vmcnt(0) before s_barrier and serialize
// each chunk on its HBM store burst.
__device__ inline void bar_lds() {
  asm volatile("s_waitcnt lgkmcnt(0)" ::: "memory");
  __builtin_amdgcn_s_barrier();
  asm volatile("" ::: "memory");
}

// ---------------------------------------------------------------------------
// K0: split weights into bf16 hi/lo (once per call).
// rows 0..255 Wq, 256..511 Wk, 512..575 Wv (256-wide); 576..831 Wh (64-wide).
// ---------------------------------------------------------------------------
__global__ __launch_bounds__(256) void wsplit_kernel(
    const float* __restrict__ Wq, const float* __restrict__ Wk,
    const float* __restrict__ Wv, const float* __restrict__ Wh,
    ushort* __restrict__ wqh, ushort* __restrict__ wql,
    ushort* __restrict__ wkh, ushort* __restrict__ wkl,
    ushort* __restrict__ wvh, ushort* __restrict__ wvl,
    ushort* __restrict__ whh, ushort* __restrict__ whl) {
  const int row = blockIdx.x;  // 0..831
  const int t = threadIdx.x;
  if (row < 576) {
    const float* src; ushort* dh; ushort* dl; int r;
    if (row < 256) { src = Wq; dh = wqh; dl = wql; r = row; }
    else if (row < 512) { src = Wk; dh = wkh; dl = wkl; r = row - 256; }
    else { src = Wv; dh = wvh; dl = wvl; r = row - 512; }
    const float v = src[(size_t)r * DM + t];
    const ushort hi = f2b(v);
    dh[(size_t)r * DM + t] = hi;
    dl[(size_t)r * DM + t] = f2b(v - b2f(hi));
  } else if (t < 64) {
    const int r = row - 576;  // Wh row, 64 wide
    const float v = Wh[(size_t)r * DK + t];
    const ushort hi = f2b(v);
    whh[(size_t)r * DK + t] = hi;
    whl[(size_t)r * DK + t] = f2b(v - b2f(hi));
  }
}

// ---------------------------------------------------------------------------
// K1a: q AND k projection GEMM, split-bf16. Grid 1024:
// bid>>9 selects q/k; (bid&511) = head*128 + tile.
// ---------------------------------------------------------------------------
__global__ __launch_bounds__(256) void proj_qk2(
    const float* __restrict__ q, const float* __restrict__ k,
    const ushort* __restrict__ wqh, const ushort* __restrict__ wql,
    const ushort* __restrict__ wkh, const ushort* __restrict__ wkl,
    ushort* __restrict__ qhi, ushort* __restrict__ qlo,
    ushort* __restrict__ khi, ushort* __restrict__ klo) {
  const int which = blockIdx.x >> 9;
  const int sub = blockIdx.x & 511;
  const int tile = sub & 127;
  const int h = sub >> 7;
  const float* x = which ? k : q;
  const ushort* wh = which ? wkh : wqh;
  const ushort* wl = which ? wkl : wql;
  ushort* ohi = which ? khi : qhi;
  ushort* olo = which ? klo : qlo;

  const int wid = threadIdx.x >> 6;
  const int lane = threadIdx.x & 63;
  const int l15 = lane & 15, g = lane >> 4;
  const int row0 = tile * 64 + wid * 16;

  bf16x8 ah[8], al[8];
  const float* xrow = x + (size_t)(row0 + l15) * DM;
#pragma unroll
  for (int ks = 0; ks < 8; ++ks) {
    float4 f0 = *(const float4*)(xrow + ks * 32 + 8 * g);
    float4 f1 = *(const float4*)(xrow + ks * 32 + 8 * g + 4);
    float fv[8] = {f0.x, f0.y, f0.z, f0.w, f1.x, f1.y, f1.z, f1.w};
    bf16x8 h8, l8;
#pragma unroll
    for (int j = 0; j < 8; ++j) {
      ushort hu = f2b(fv[j]);
      h8[j] = (short)hu;
      l8[j] = (short)f2b(fv[j] - b2f(hu));
    }
    ah[ks] = h8; al[ks] = l8;
  }

  f32x4 acc[4];
#pragma unroll
  for (int n = 0; n < 4; ++n) acc[n] = (f32x4){0.f, 0.f, 0.f, 0.f};

#pragma unroll
  for (int n = 0; n < 4; ++n) {
    const ushort* wrh = wh + (size_t)(h * DK + n * 16 + l15) * DM + 8 * g;
    const ushort* wrl = wl + (size_t)(h * DK + n * 16 + l15) * DM + 8 * g;
#pragma unroll
    for (int ks = 0; ks < 8; ++ks) {
      bf16x8 bh = ld8(wrh + ks * 32);
      bf16x8 bl = ld8(wrl + ks * 32);
      acc[n] = MFMA(ah[ks], bh, acc[n]);
      acc[n] = MFMA(al[ks], bh, acc[n]);
      acc[n] = MFMA(ah[ks], bl, acc[n]);
    }
  }

#pragma unroll
  for (int n = 0; n < 4; ++n) {
    const int e = n * 16 + l15;
#pragma unroll
    for (int r = 0; r < 4; ++r) {
      const int tok = row0 + 4 * g + r;
      const int b = tok >> 11, s = tok & (S - 1);
      const size_t idx = ((size_t)((b * H + h) * S + s)) * DK + e;
      const float val = acc[n][r];
      const ushort hu = f2b(val);
      ohi[idx] = hu;
      olo[idx] = f2b(val - b2f(hu));
    }
  }
}

// ---------------------------------------------------------------------------
// K1b: v projection GEMM (shared across heads), NF=4, grid 128.
// ---------------------------------------------------------------------------
__global__ __launch_bounds__(256) void proj_v(
    const float* __restrict__ x, const ushort* __restrict__ wh,
    const ushort* __restrict__ wl, ushort* __restrict__ vT) {
  const int wid = threadIdx.x >> 6;
  const int lane = threadIdx.x & 63;
  const int l15 = lane & 15, g = lane >> 4;
  const int row0 = blockIdx.x * 64 + wid * 16;

  bf16x8 ah[8], al[8];
  const float* xrow = x + (size_t)(row0 + l15) * DM;
#pragma unroll
  for (int ks = 0; ks < 8; ++ks) {
    float4 f0 = *(const float4*)(xrow + ks * 32 + 8 * g);
    float4 f1 = *(const float4*)(xrow + ks * 32 + 8 * g + 4);
    float fv[8] = {f0.x, f0.y, f0.z, f0.w, f1.x, f1.y, f1.z, f1.w};
    bf16x8 h8, l8;
#pragma unroll
    for (int j = 0; j < 8; ++j) {
      ushort hu = f2b(fv[j]);
      h8[j] = (short)hu;
      l8[j] = (short)f2b(fv[j] - b2f(hu));
    }
    ah[ks] = h8; al[ks] = l8;
  }

  f32x4 acc[4];
#pragma unroll
  for (int n = 0; n < 4; ++n) acc[n] = (f32x4){0.f, 0.f, 0.f, 0.f};
#pragma unroll
  for (int n = 0; n < 4; ++n) {
    const ushort* wrh = wh + (size_t)(n * 16 + l15) * DM + 8 * g;
    const ushort* wrl = wl + (size_t)(n * 16 + l15) * DM + 8 * g;
#pragma unroll
    for (int ks = 0; ks < 8; ++ks) {
      bf16x8 bh = ld8(wrh + ks * 32);
      bf16x8 bl = ld8(wrl + ks * 32);
      acc[n] = MFMA(ah[ks], bh, acc[n]);
      acc[n] = MFMA(al[ks], bh, acc[n]);
      acc[n] = MFMA(ah[ks], bl, acc[n]);
    }
  }
#pragma unroll
  for (int n = 0; n < 4; ++n) {
    const int e = n * 16 + l15;
#pragma unroll
    for (int r = 0; r < 4; ++r) {
      const int tok = row0 + 4 * g + r;
      const int b = tok >> 11, s = tok & (S - 1);
      vT[((size_t)b * DK + e) * S + s] = f2b(acc[n][r]);
    }
  }
}

// ---------------------------------------------------------------------------
// K2: attention v4.2 — R13 structure; chunk-loop barriers replaced with
// LDS-only barriers (no vmcnt drain of the NT store stream).
// ---------------------------------------------------------------------------
__global__ __launch_bounds__(512) void attn_kernel(
    const ushort* __restrict__ qhi, const ushort* __restrict__ qlo,
    const ushort* __restrict__ khi, const ushort* __restrict__ klo,
    const ushort* __restrict__ vT,
    float* __restrict__ attn_out, float* __restrict__ heads) {
  __shared__ __align__(16) u8 kst[2][8192];  // p1: 64-key hi; p2: 32-key hi|lo(+4096)
  __shared__ __align__(16) u8 vst[2][5120];  // per buf: [64 dims][80B padded]

  const int tid = threadIdx.x;
  const int wid = tid >> 6;
  const int lane = tid & 63;
  const int l15 = lane & 15, g = lane >> 4;
  const int bid = blockIdx.x;
  const int swz = (bid & 7) * 32 + (bid >> 3);
  const int qt = swz & 15;
  const int h = (swz >> 4) & 3;
  const int b = swz >> 6;
  const int row0 = qt * 128 + wid * 16;
  const float SC = 0.125f;  // 1/sqrt(64)

  const size_t bh = (size_t)(b * H + h);
  const ushort* qbh = qhi + (bh * S + row0 + l15) * DK;
  const ushort* qbl = qlo + (bh * S + row0 + l15) * DK;
  const bf16x8 aqh0 = ld8(qbh + 8 * g), aqh1 = ld8(qbh + 32 + 8 * g);
  const bf16x8 aql0 = ld8(qbl + 8 * g), aql1 = ld8(qbl + 32 + 8 * g);
  const ushort* kbh = khi + bh * S * DK;
  const ushort* kbl = klo + bh * S * DK;
  const ushort* vTb = vT + (size_t)b * DK * S;

  // pass-2 staging maps (pre-swizzled global source -> linear LDS dest)
  const int role = tid >> 8;
  const int t8 = tid & 255;
  const int skey = t8 >> 3, sslot = t8 & 7;
  const int sgslot = sslot ^ (skey & 7);
  const ushort* ksrc = role ? kbl : kbh;
  const int kdst = role * 4096 + t8 * 16;
  const int sdim = tid >> 3, sk8 = tid & 7;

  // pass-1 staging map: 64 keys/chunk, all 512 threads
  const int skey64 = tid >> 3;                    // 0..63
  const int sgslot64 = (tid & 7) ^ (skey64 & 7);  // pre-swizzled slot

  const int fx0 = l15 * 128 + ((g ^ (l15 & 7)) << 4);
  const int fx1 = l15 * 128 + (((4 + g) ^ (l15 & 7)) << 4);
  const int fy0 = fx0 + 2048;
  const int fy1 = fx1 + 2048;

  // ---- pass 1: per-row sum of exp(score_hi * SC); 64-key chunks ----
  float ssum = 0.f;
  *(bf16x8*)(&kst[0][tid * 16]) = ld8(kbh + (size_t)skey64 * DK + sgslot64 * 8);
  bar_lds();
  for (int c = 0; c < 32; ++c) {
    const int p = c & 1;
    bf16x8 rkh;
    if (c + 1 < 32)
      rkh = ld8(kbh + (size_t)((c + 1) * 64 + skey64) * DK + sgslot64 * 8);
    const u8* kb = kst[p];
#pragma unroll
    for (int kg = 0; kg < 4; ++kg) {
      bf16x8 bh0 = *(const bf16x8*)(kb + kg * 2048 + fx0);
      bf16x8 bh1 = *(const bf16x8*)(kb + kg * 2048 + fx1);
      f32x4 a = {0.f, 0.f, 0.f, 0.f};
      a = MFMA(bh0, aqh0, a); a = MFMA(bh1, aqh1, a);
      ssum += (__expf(a[0] * SC) + __expf(a[1] * SC)) +
              (__expf(a[2] * SC) + __expf(a[3] * SC));
    }
    if (c + 1 < 32) *(bf16x8*)(&kst[p ^ 1][tid * 16]) = rkh;
    bar_lds();
  }
  ssum += __shfl_xor(ssum, 16, 64);
  ssum += __shfl_xor(ssum, 32, 64);
  const float inv = 1.f / ssum;

  // ---- pass 2: 3-term scores, normalize, NT attn stores, PV ----
  f32x4 hacc[4] = {{0.f, 0.f, 0.f, 0.f}, {0.f, 0.f, 0.f, 0.f},
                   {0.f, 0.f, 0.f, 0.f}, {0.f, 0.f, 0.f, 0.f}};
  float* arow = attn_out + (((size_t)(b * S + row0 + l15)) * H + h) * S;

  *(bf16x8*)(&kst[0][kdst]) = ld8(ksrc + (size_t)skey * DK + sgslot * 8);
  *(bf16x4*)(&vst[0][sdim * 80 + sk8 * 8]) = ld4(vTb + (size_t)sdim * S + sk8 * 4);
  bar_lds();

  for (int c = 0; c < 64; ++c) {
    const int p = c & 1;
    const int t0 = c * 32;
    bf16x8 rk; bf16x4 rv;
    if (c + 1 < 64) {
      const size_t t1 = (size_t)(c + 1) * 32;
      rk = ld8(ksrc + (t1 + skey) * DK + sgslot * 8);
      rv = ld4(vTb + (size_t)sdim * S + t1 + sk8 * 4);
    }
    const u8* kb = kst[p];
    const u8* vb = vst[p];
    bf16x8 bh0 = *(const bf16x8*)(kb + fx0);
    bf16x8 bh1 = *(const bf16x8*)(kb + fx1);
    bf16x8 ch0 = *(const bf16x8*)(kb + fy0);
    bf16x8 ch1 = *(const bf16x8*)(kb + fy1);
    bf16x8 bl0 = *(const bf16x8*)(kb + 4096 + fx0);
    bf16x8 bl1 = *(const bf16x8*)(kb + 4096 + fx1);
    bf16x8 cl0 = *(const bf16x8*)(kb + 4096 + fy0);
    bf16x8 cl1 = *(const bf16x8*)(kb + 4096 + fy1);
    f32x4 a0 = {0.f, 0.f, 0.f, 0.f}, a1 = {0.f, 0.f, 0.f, 0.f};
    a0 = MFMA(bh0, aqh0, a0); a0 = MFMA(bh1, aqh1, a0);
    a0 = MFMA(bl0, aqh0, a0); a0 = MFMA(bl1, aqh1, a0);
    a0 = MFMA(bh0, aql0, a0); a0 = MFMA(bh1, aql1, a0);
    a1 = MFMA(ch0, aqh0, a1); a1 = MFMA(ch1, aqh1, a1);
    a1 = MFMA(cl0, aqh0, a1); a1 = MFMA(cl1, aqh1, a1);
    a1 = MFMA(ch0, aql0, a1); a1 = MFMA(ch1, aql1, a1);

    const float p0 = __expf(a0[0] * SC) * inv;
    const float p1 = __expf(a0[1] * SC) * inv;
    const float p2 = __expf(a0[2] * SC) * inv;
    const float p3 = __expf(a0[3] * SC) * inv;
    const float p4 = __expf(a1[0] * SC) * inv;
    const float p5 = __expf(a1[1] * SC) * inv;
    const float p6 = __expf(a1[2] * SC) * inv;
    const float p7 = __expf(a1[3] * SC) * inv;

    f32x4 o0 = {p0, p1, p2, p3};
    f32x4 o1 = {p4, p5, p6, p7};
    __builtin_nontemporal_store(o0, (f32x4*)(arow + t0 + 4 * g));
    __builtin_nontemporal_store(o1, (f32x4*)(arow + t0 + 16 + 4 * g));

    bf16x4 pa0, pa1;
    pa0[0] = (short)f2b(p0); pa0[1] = (short)f2b(p1);
    pa0[2] = (short)f2b(p2); pa0[3] = (short)f2b(p3);
    pa1[0] = (short)f2b(p4); pa1[1] = (short)f2b(p5);
    pa1[2] = (short)f2b(p6); pa1[3] = (short)f2b(p7);

#pragma unroll
    for (int n = 0; n < 4; ++n) {
      bf16x4 vb0 = *(const bf16x4*)(vb + (n * 16 + l15) * 80 + 8 * g);
      bf16x4 vb1 = *(const bf16x4*)(vb + (n * 16 + l15) * 80 + 32 + 8 * g);
      hacc[n] = MFMA16(pa0, vb0, hacc[n]);
      hacc[n] = MFMA16(pa1, vb1, hacc[n]);
    }

    if (c + 1 < 64) {
      *(bf16x8*)(&kst[p ^ 1][kdst]) = rk;
      *(bf16x4*)(&vst[p ^ 1][sdim * 80 + sk8 * 8]) = rv;
    }
    bar_lds();
  }

#pragma unroll
  for (int n = 0; n < 4; ++n)
#pragma unroll
    for (int r = 0; r < 4; ++r)
      heads[(bh * S + row0 + 4 * g + r) * DK + n * 16 + l15] = hacc[n][r];
}

// ---------------------------------------------------------------------------
// K3: head-mean + output projection as MFMA GEMM (split-bf16, 3-term).
// Grid 512 x 256 thr: block = 16 tokens; wave w = output quarter [64w,64w+64).
// ---------------------------------------------------------------------------
__global__ __launch_bounds__(256) void out_mfma(
    const float* __restrict__ heads, const ushort* __restrict__ whh,
    const ushort* __restrict__ whl, float* __restrict__ out) {
  const int wid = threadIdx.x >> 6;  // output quarter
  const int lane = threadIdx.x & 63;
  const int l15 = lane & 15, g = lane >> 4;
  const int row0 = blockIdx.x * 16;
  const int tok = row0 + l15;
  const int b = tok >> 11, s = tok & (S - 1);

  bf16x8 ah[2], al[2];
  const float* hp0 = heads + ((size_t)((b * H + 0) * S + s)) * DK;
  const size_t hstride = (size_t)S * DK;
#pragma unroll
  for (int c = 0; c < 2; ++c) {
    const int d0 = c * 32 + 8 * g;
    float4 s0 = {0.f, 0.f, 0.f, 0.f}, s1 = {0.f, 0.f, 0.f, 0.f};
#pragma unroll
    for (int hh = 0; hh < H; ++hh) {
      const float* hp = hp0 + hh * hstride + d0;
      float4 x0 = *(const float4*)hp;
      float4 x1 = *(const float4*)(hp + 4);
      s0.x += x0.x; s0.y += x0.y; s0.z += x0.z; s0.w += x0.w;
      s1.x += x1.x; s1.y += x1.y; s1.z += x1.z; s1.w += x1.w;
    }
    float fv[8] = {s0.x * 0.25f, s0.y * 0.25f, s0.z * 0.25f, s0.w * 0.25f,
                   s1.x * 0.25f, s1.y * 0.25f, s1.z * 0.25f, s1.w * 0.25f};
    bf16x8 h8, l8;
#pragma unroll
    for (int j = 0; j < 8; ++j) {
      ushort hu = f2b(fv[j]);
      h8[j] = (short)hu;
      l8[j] = (short)f2b(fv[j] - b2f(hu));
    }
    ah[c] = h8; al[c] = l8;
  }

  f32x4 acc[4];
#pragma unroll
  for (int n = 0; n < 4; ++n) acc[n] = (f32x4){0.f, 0.f, 0.f, 0.f};
#pragma unroll
  for (int n = 0; n < 4; ++n) {
    const int f = wid * 64 + n * 16 + l15;
    const ushort* brh = whh + (size_t)f * DK + 8 * g;
    const ushort* brl = whl + (size_t)f * DK + 8 * g;
#pragma unroll
    for (int c = 0; c < 2; ++c) {
      bf16x8 bh = ld8(brh + c * 32);
      bf16x8 bl = ld8(brl + c * 32);
      acc[n] = MFMA(ah[c], bh, acc[n]);
      acc[n] = MFMA(al[c], bh, acc[n]);
      acc[n] = MFMA(ah[c], bl, acc[n]);
    }
  }

#pragma unroll
  for (int n = 0; n < 4; ++n) {
    const int f = wid * 64 + n * 16 + l15;
#pragma unroll
    for (int r = 0; r < 4; ++r)
      out[(size_t)(row0 + 4 * g + r) * DM + f] = acc[n][r];
  }
}

extern "C" void kernel_launch(void* const* d_in, const int* in_sizes, int n_in,
                              void* d_out, int out_size, void* d_ws, size_t ws_size,
                              hipStream_t stream) {
  const float* q = (const float*)d_in[0];
  const float* k = (const float*)d_in[1];
  const float* v = (const float*)d_in[2];
  const float* Wq = (const float*)d_in[3];
  const float* Wk = (const float*)d_in[4];
  const float* Wv = (const float*)d_in[5];
  const float* Wh = (const float*)d_in[6];

  float* out = (float*)d_out;                  // [B,S,DM]
  float* attn_out = out + (size_t)B * S * DM;  // [B,S,H,S]

  const size_t n1 = (size_t)B * H * S * DK;  // 2,097,152
  ushort* qhi = (ushort*)d_ws;
  ushort* qlo = qhi + n1;
  ushort* khi = qlo + n1;
  ushort* klo = khi + n1;
  ushort* vT = klo + n1;                              // B*DK*S
  float* heads = (float*)(vT + (size_t)B * DK * S);   // [B,H,S,DK] fp32
  ushort* wqh = (ushort*)(heads + n1);                // 65536 each
  ushort* wql = wqh + (size_t)H * DK * DM;
  ushort* wkh = wql + (size_t)H * DK * DM;
  ushort* wkl = wkh + (size_t)H * DK * DM;
  ushort* wvh = wkl + (size_t)H * DK * DM;            // 16384 each
  ushort* wvl = wvh + (size_t)DK * DM;
  ushort* whh = wvl + (size_t)DK * DM;                // 16384 each
  ushort* whl = whh + (size_t)DM * DK;

  wsplit_kernel<<<832, 256, 0, stream>>>(Wq, Wk, Wv, Wh, wqh, wql, wkh, wkl,
                                         wvh, wvl, whh, whl);
  proj_qk2<<<1024, 256, 0, stream>>>(q, k, wqh, wql, wkh, wkl, qhi, qlo, khi, klo);
  proj_v<<<128, 256, 0, stream>>>(v, wvh, wvl, vT);
  attn_kernel<<<256, 512, 0, stream>>>(qhi, qlo, khi, klo, vT, attn_out, heads);
  out_mfma<<<512, 256, 0, stream>>>(heads, whh, whl, out);
}

// Round 15
// 164.631 us; speedup vs baseline: 1.0185x; 1.0185x over previous
//
#include <hip/hip_runtime.h>
#include <hip/hip_bf16.h>
#include <math.h>

#define B 4
#define S 2048
#define H 4
#define DK 64
#define DM 256

using bf16x8 = __attribute__((ext_vector_type(8))) short;
using bf16x4 = __attribute__((ext_vector_type(4))) short;
using f32x4 = __attribute__((ext_vector_type(4))) float;
typedef unsigned char u8;

__device__ inline ushort f2b(float f) {
  __hip_bfloat16 h = __float2bfloat16(f);
  ushort u; __builtin_memcpy(&u, &h, 2); return u;
}
__device__ inline float b2f(ushort u) {
  __hip_bfloat16 h; __builtin_memcpy(&h, &u, 2); return __bfloat162float(h);
}
__device__ inline bf16x8 ld8(const ushort* p) {
  return *reinterpret_cast<const bf16x8*>(p);
}
__device__ inline bf16x4 ld4(const ushort* p) {
  return *reinterpret_cast<const bf16x4*>(p);
}
#define MFMA(a, b, c) __builtin_amdgcn_mfma_f32_16x16x32_bf16((a), (b), (c), 0, 0, 0)

#if __has_builtin(__builtin_amdgcn_mfma_f32_16x16x16bf16_1k)
__device__ inline f32x4 MFMA16(bf16x4 a, bf16x4 b, f32x4 c) {
  return __builtin_amdgcn_mfma_f32_16x16x16bf16_1k(a, b, c, 0, 0, 0);
}
#else
__device__ inline f32x4 MFMA16(bf16x4 a, bf16x4 b, f32x4 c) {
  asm("v_mfma_f32_16x16x16_bf16 %0, %1, %2, %0" : "+v"(c) : "v"(a), "v"(b));
  return c;
}
#endif

// ---------------------------------------------------------------------------
// K0: split weights into bf16 hi/lo (once per call).
// rows 0..255 Wq, 256..511 Wk, 512..575 Wv (256-wide); 576..831 Wh (64-wide).
// ---------------------------------------------------------------------------
__global__ __launch_bounds__(256) void wsplit_kernel(
    const float* __restrict__ Wq, const float* __restrict__ Wk,
    const float* __restrict__ Wv, const float* __restrict__ Wh,
    ushort* __restrict__ wqh, ushort* __restrict__ wql,
    ushort* __restrict__ wkh, ushort* __restrict__ wkl,
    ushort* __restrict__ wvh, ushort* __restrict__ wvl,
    ushort* __restrict__ whh, ushort* __restrict__ whl) {
  const int row = blockIdx.x;  // 0..831
  const int t = threadIdx.x;
  if (row < 576) {
    const float* src; ushort* dh; ushort* dl; int r;
    if (row < 256) { src = Wq; dh = wqh; dl = wql; r = row; }
    else if (row < 512) { src = Wk; dh = wkh; dl = wkl; r = row - 256; }
    else { src = Wv; dh = wvh; dl = wvl; r = row - 512; }
    const float v = src[(size_t)r * DM + t];
    const ushort hi = f2b(v);
    dh[(size_t)r * DM + t] = hi;
    dl[(size_t)r * DM + t] = f2b(v - b2f(hi));
  } else if (t < 64) {
    const int r = row - 576;  // Wh row, 64 wide
    const float v = Wh[(size_t)r * DK + t];
    const ushort hi = f2b(v);
    whh[(size_t)r * DK + t] = hi;
    whl[(size_t)r * DK + t] = f2b(v - b2f(hi));
  }
}

// ---------------------------------------------------------------------------
// K1a: q AND k projection GEMM, split-bf16. Grid 1024:
// bid>>9 selects q/k; (bid&511) = head*128 + tile.
// ---------------------------------------------------------------------------
__global__ __launch_bounds__(256) void proj_qk2(
    const float* __restrict__ q, const float* __restrict__ k,
    const ushort* __restrict__ wqh, const ushort* __restrict__ wql,
    const ushort* __restrict__ wkh, const ushort* __restrict__ wkl,
    ushort* __restrict__ qhi, ushort* __restrict__ qlo,
    ushort* __restrict__ khi, ushort* __restrict__ klo) {
  const int which = blockIdx.x >> 9;
  const int sub = blockIdx.x & 511;
  const int tile = sub & 127;
  const int h = sub >> 7;
  const float* x = which ? k : q;
  const ushort* wh = which ? wkh : wqh;
  const ushort* wl = which ? wkl : wql;
  ushort* ohi = which ? khi : qhi;
  ushort* olo = which ? klo : qlo;

  const int wid = threadIdx.x >> 6;
  const int lane = threadIdx.x & 63;
  const int l15 = lane & 15, g = lane >> 4;
  const int row0 = tile * 64 + wid * 16;

  bf16x8 ah[8], al[8];
  const float* xrow = x + (size_t)(row0 + l15) * DM;
#pragma unroll
  for (int ks = 0; ks < 8; ++ks) {
    float4 f0 = *(const float4*)(xrow + ks * 32 + 8 * g);
    float4 f1 = *(const float4*)(xrow + ks * 32 + 8 * g + 4);
    float fv[8] = {f0.x, f0.y, f0.z, f0.w, f1.x, f1.y, f1.z, f1.w};
    bf16x8 h8, l8;
#pragma unroll
    for (int j = 0; j < 8; ++j) {
      ushort hu = f2b(fv[j]);
      h8[j] = (short)hu;
      l8[j] = (short)f2b(fv[j] - b2f(hu));
    }
    ah[ks] = h8; al[ks] = l8;
  }

  f32x4 acc[4];
#pragma unroll
  for (int n = 0; n < 4; ++n) acc[n] = (f32x4){0.f, 0.f, 0.f, 0.f};

#pragma unroll
  for (int n = 0; n < 4; ++n) {
    const ushort* wrh = wh + (size_t)(h * DK + n * 16 + l15) * DM + 8 * g;
    const ushort* wrl = wl + (size_t)(h * DK + n * 16 + l15) * DM + 8 * g;
#pragma unroll
    for (int ks = 0; ks < 8; ++ks) {
      bf16x8 bh = ld8(wrh + ks * 32);
      bf16x8 bl = ld8(wrl + ks * 32);
      acc[n] = MFMA(ah[ks], bh, acc[n]);
      acc[n] = MFMA(al[ks], bh, acc[n]);
      acc[n] = MFMA(ah[ks], bl, acc[n]);
    }
  }

#pragma unroll
  for (int n = 0; n < 4; ++n) {
    const int e = n * 16 + l15;
#pragma unroll
    for (int r = 0; r < 4; ++r) {
      const int tok = row0 + 4 * g + r;
      const int b = tok >> 11, s = tok & (S - 1);
      const size_t idx = ((size_t)((b * H + h) * S + s)) * DK + e;
      const float val = acc[n][r];
      const ushort hu = f2b(val);
      ohi[idx] = hu;
      olo[idx] = f2b(val - b2f(hu));
    }
  }
}

// ---------------------------------------------------------------------------
// K1b: v projection GEMM (shared across heads), NF=4, grid 128.
// ---------------------------------------------------------------------------
__global__ __launch_bounds__(256) void proj_v(
    const float* __restrict__ x, const ushort* __restrict__ wh,
    const ushort* __restrict__ wl, ushort* __restrict__ vT) {
  const int wid = threadIdx.x >> 6;
  const int lane = threadIdx.x & 63;
  const int l15 = lane & 15, g = lane >> 4;
  const int row0 = blockIdx.x * 64 + wid * 16;

  bf16x8 ah[8], al[8];
  const float* xrow = x + (size_t)(row0 + l15) * DM;
#pragma unroll
  for (int ks = 0; ks < 8; ++ks) {
    float4 f0 = *(const float4*)(xrow + ks * 32 + 8 * g);
    float4 f1 = *(const float4*)(xrow + ks * 32 + 8 * g + 4);
    float fv[8] = {f0.x, f0.y, f0.z, f0.w, f1.x, f1.y, f1.z, f1.w};
    bf16x8 h8, l8;
#pragma unroll
    for (int j = 0; j < 8; ++j) {
      ushort hu = f2b(fv[j]);
      h8[j] = (short)hu;
      l8[j] = (short)f2b(fv[j] - b2f(hu));
    }
    ah[ks] = h8; al[ks] = l8;
  }

  f32x4 acc[4];
#pragma unroll
  for (int n = 0; n < 4; ++n) acc[n] = (f32x4){0.f, 0.f, 0.f, 0.f};
#pragma unroll
  for (int n = 0; n < 4; ++n) {
    const ushort* wrh = wh + (size_t)(n * 16 + l15) * DM + 8 * g;
    const ushort* wrl = wl + (size_t)(n * 16 + l15) * DM + 8 * g;
#pragma unroll
    for (int ks = 0; ks < 8; ++ks) {
      bf16x8 bh = ld8(wrh + ks * 32);
      bf16x8 bl = ld8(wrl + ks * 32);
      acc[n] = MFMA(ah[ks], bh, acc[n]);
      acc[n] = MFMA(al[ks], bh, acc[n]);
      acc[n] = MFMA(ah[ks], bl, acc[n]);
    }
  }
#pragma unroll
  for (int n = 0; n < 4; ++n) {
    const int e = n * 16 + l15;
#pragma unroll
    for (int r = 0; r < 4; ++r) {
      const int tok = row0 + 4 * g + r;
      const int b = tok >> 11, s = tok & (S - 1);
      vT[((size_t)b * DK + e) * S + s] = f2b(acc[n][r]);
    }
  }
}

// ---------------------------------------------------------------------------
// K2: attention v4.1 (R13 exact) — 128 q-rows/block, 8 waves, LDS-staged K/V
// shared by all waves. Pass 1: 64-key chunks (all 512 threads stage, 32
// barriers). Pass 2: 32-key chunks (3-term scores, NT attn stores, PV).
// ---------------------------------------------------------------------------
__global__ __launch_bounds__(512) void attn_kernel(
    const ushort* __restrict__ qhi, const ushort* __restrict__ qlo,
    const ushort* __restrict__ khi, const ushort* __restrict__ klo,
    const ushort* __restrict__ vT,
    float* __restrict__ attn_out, float* __restrict__ heads) {
  __shared__ __align__(16) u8 kst[2][8192];  // p1: 64-key hi; p2: 32-key hi|lo(+4096)
  __shared__ __align__(16) u8 vst[2][5120];  // per buf: [64 dims][80B padded]

  const int tid = threadIdx.x;
  const int wid = tid >> 6;
  const int lane = tid & 63;
  const int l15 = lane & 15, g = lane >> 4;
  const int bid = blockIdx.x;
  const int swz = (bid & 7) * 32 + (bid >> 3);
  const int qt = swz & 15;
  const int h = (swz >> 4) & 3;
  const int b = swz >> 6;
  const int row0 = qt * 128 + wid * 16;
  const float SC = 0.125f;  // 1/sqrt(64)

  const size_t bh = (size_t)(b * H + h);
  const ushort* qbh = qhi + (bh * S + row0 + l15) * DK;
  const ushort* qbl = qlo + (bh * S + row0 + l15) * DK;
  const bf16x8 aqh0 = ld8(qbh + 8 * g), aqh1 = ld8(qbh + 32 + 8 * g);
  const bf16x8 aql0 = ld8(qbl + 8 * g), aql1 = ld8(qbl + 32 + 8 * g);
  const ushort* kbh = khi + bh * S * DK;
  const ushort* kbl = klo + bh * S * DK;
  const ushort* vTb = vT + (size_t)b * DK * S;

  // pass-2 staging maps (pre-swizzled global source -> linear LDS dest)
  const int role = tid >> 8;
  const int t8 = tid & 255;
  const int skey = t8 >> 3, sslot = t8 & 7;
  const int sgslot = sslot ^ (skey & 7);
  const ushort* ksrc = role ? kbl : kbh;
  const int kdst = role * 4096 + t8 * 16;
  const int sdim = tid >> 3, sk8 = tid & 7;

  // pass-1 staging map: 64 keys/chunk, all 512 threads
  const int skey64 = tid >> 3;                    // 0..63
  const int sgslot64 = (tid & 7) ^ (skey64 & 7);  // pre-swizzled slot

  const int fx0 = l15 * 128 + ((g ^ (l15 & 7)) << 4);
  const int fx1 = l15 * 128 + (((4 + g) ^ (l15 & 7)) << 4);
  const int fy0 = fx0 + 2048;
  const int fy1 = fx1 + 2048;

  // ---- pass 1: per-row sum of exp(score_hi * SC); 64-key chunks ----
  float ssum = 0.f;
  *(bf16x8*)(&kst[0][tid * 16]) = ld8(kbh + (size_t)skey64 * DK + sgslot64 * 8);
  __syncthreads();
  for (int c = 0; c < 32; ++c) {
    const int p = c & 1;
    bf16x8 rkh;
    if (c + 1 < 32)
      rkh = ld8(kbh + (size_t)((c + 1) * 64 + skey64) * DK + sgslot64 * 8);
    const u8* kb = kst[p];
#pragma unroll
    for (int kg = 0; kg < 4; ++kg) {
      bf16x8 bh0 = *(const bf16x8*)(kb + kg * 2048 + fx0);
      bf16x8 bh1 = *(const bf16x8*)(kb + kg * 2048 + fx1);
      f32x4 a = {0.f, 0.f, 0.f, 0.f};
      a = MFMA(bh0, aqh0, a); a = MFMA(bh1, aqh1, a);
      ssum += (__expf(a[0] * SC) + __expf(a[1] * SC)) +
              (__expf(a[2] * SC) + __expf(a[3] * SC));
    }
    if (c + 1 < 32) *(bf16x8*)(&kst[p ^ 1][tid * 16]) = rkh;
    __syncthreads();
  }
  ssum += __shfl_xor(ssum, 16, 64);
  ssum += __shfl_xor(ssum, 32, 64);
  const float inv = 1.f / ssum;

  // ---- pass 2: 3-term scores, normalize, NT attn stores, PV ----
  f32x4 hacc[4] = {{0.f, 0.f, 0.f, 0.f}, {0.f, 0.f, 0.f, 0.f},
                   {0.f, 0.f, 0.f, 0.f}, {0.f, 0.f, 0.f, 0.f}};
  float* arow = attn_out + (((size_t)(b * S + row0 + l15)) * H + h) * S;

  *(bf16x8*)(&kst[0][kdst]) = ld8(ksrc + (size_t)skey * DK + sgslot * 8);
  *(bf16x4*)(&vst[0][sdim * 80 + sk8 * 8]) = ld4(vTb + (size_t)sdim * S + sk8 * 4);
  __syncthreads();

  for (int c = 0; c < 64; ++c) {
    const int p = c & 1;
    const int t0 = c * 32;
    bf16x8 rk; bf16x4 rv;
    if (c + 1 < 64) {
      const size_t t1 = (size_t)(c + 1) * 32;
      rk = ld8(ksrc + (t1 + skey) * DK + sgslot * 8);
      rv = ld4(vTb + (size_t)sdim * S + t1 + sk8 * 4);
    }
    const u8* kb = kst[p];
    const u8* vb = vst[p];
    bf16x8 bh0 = *(const bf16x8*)(kb + fx0);
    bf16x8 bh1 = *(const bf16x8*)(kb + fx1);
    bf16x8 ch0 = *(const bf16x8*)(kb + fy0);
    bf16x8 ch1 = *(const bf16x8*)(kb + fy1);
    bf16x8 bl0 = *(const bf16x8*)(kb + 4096 + fx0);
    bf16x8 bl1 = *(const bf16x8*)(kb + 4096 + fx1);
    bf16x8 cl0 = *(const bf16x8*)(kb + 4096 + fy0);
    bf16x8 cl1 = *(const bf16x8*)(kb + 4096 + fy1);
    f32x4 a0 = {0.f, 0.f, 0.f, 0.f}, a1 = {0.f, 0.f, 0.f, 0.f};
    a0 = MFMA(bh0, aqh0, a0); a0 = MFMA(bh1, aqh1, a0);
    a0 = MFMA(bl0, aqh0, a0); a0 = MFMA(bl1, aqh1, a0);
    a0 = MFMA(bh0, aql0, a0); a0 = MFMA(bh1, aql1, a0);
    a1 = MFMA(ch0, aqh0, a1); a1 = MFMA(ch1, aqh1, a1);
    a1 = MFMA(cl0, aqh0, a1); a1 = MFMA(cl1, aqh1, a1);
    a1 = MFMA(ch0, aql0, a1); a1 = MFMA(ch1, aql1, a1);

    const float p0 = __expf(a0[0] * SC) * inv;
    const float p1 = __expf(a0[1] * SC) * inv;
    const float p2 = __expf(a0[2] * SC) * inv;
    const float p3 = __expf(a0[3] * SC) * inv;
    const float p4 = __expf(a1[0] * SC) * inv;
    const float p5 = __expf(a1[1] * SC) * inv;
    const float p6 = __expf(a1[2] * SC) * inv;
    const float p7 = __expf(a1[3] * SC) * inv;

    f32x4 o0 = {p0, p1, p2, p3};
    f32x4 o1 = {p4, p5, p6, p7};
    __builtin_nontemporal_store(o0, (f32x4*)(arow + t0 + 4 * g));
    __builtin_nontemporal_store(o1, (f32x4*)(arow + t0 + 16 + 4 * g));

    bf16x4 pa0, pa1;
    pa0[0] = (short)f2b(p0); pa0[1] = (short)f2b(p1);
    pa0[2] = (short)f2b(p2); pa0[3] = (short)f2b(p3);
    pa1[0] = (short)f2b(p4); pa1[1] = (short)f2b(p5);
    pa1[2] = (short)f2b(p6); pa1[3] = (short)f2b(p7);

#pragma unroll
    for (int n = 0; n < 4; ++n) {
      bf16x4 vb0 = *(const bf16x4*)(vb + (n * 16 + l15) * 80 + 8 * g);
      bf16x4 vb1 = *(const bf16x4*)(vb + (n * 16 + l15) * 80 + 32 + 8 * g);
      hacc[n] = MFMA16(pa0, vb0, hacc[n]);
      hacc[n] = MFMA16(pa1, vb1, hacc[n]);
    }

    if (c + 1 < 64) {
      *(bf16x8*)(&kst[p ^ 1][kdst]) = rk;
      *(bf16x4*)(&vst[p ^ 1][sdim * 80 + sk8 * 8]) = rv;
    }
    __syncthreads();
  }

#pragma unroll
  for (int n = 0; n < 4; ++n)
#pragma unroll
    for (int r = 0; r < 4; ++r)
      heads[(bh * S + row0 + 4 * g + r) * DK + n * 16 + l15] = hacc[n][r];
}

// ---------------------------------------------------------------------------
// K3: head-mean + output projection as MFMA GEMM (split-bf16, 3-term).
// Grid 512 x 256 thr: block = 16 tokens; wave w = output quarter [64w,64w+64).
// ---------------------------------------------------------------------------
__global__ __launch_bounds__(256) void out_mfma(
    const float* __restrict__ heads, const ushort* __restrict__ whh,
    const ushort* __restrict__ whl, float* __restrict__ out) {
  const int wid = threadIdx.x >> 6;  // output quarter
  const int lane = threadIdx.x & 63;
  const int l15 = lane & 15, g = lane >> 4;
  const int row0 = blockIdx.x * 16;
  const int tok = row0 + l15;
  const int b = tok >> 11, s = tok & (S - 1);

  bf16x8 ah[2], al[2];
  const float* hp0 = heads + ((size_t)((b * H + 0) * S + s)) * DK;
  const size_t hstride = (size_t)S * DK;
#pragma unroll
  for (int c = 0; c < 2; ++c) {
    const int d0 = c * 32 + 8 * g;
    float4 s0 = {0.f, 0.f, 0.f, 0.f}, s1 = {0.f, 0.f, 0.f, 0.f};
#pragma unroll
    for (int hh = 0; hh < H; ++hh) {
      const float* hp = hp0 + hh * hstride + d0;
      float4 x0 = *(const float4*)hp;
      float4 x1 = *(const float4*)(hp + 4);
      s0.x += x0.x; s0.y += x0.y; s0.z += x0.z; s0.w += x0.w;
      s1.x += x1.x; s1.y += x1.y; s1.z += x1.z; s1.w += x1.w;
    }
    float fv[8] = {s0.x * 0.25f, s0.y * 0.25f, s0.z * 0.25f, s0.w * 0.25f,
                   s1.x * 0.25f, s1.y * 0.25f, s1.z * 0.25f, s1.w * 0.25f};
    bf16x8 h8, l8;
#pragma unroll
    for (int j = 0; j < 8; ++j) {
      ushort hu = f2b(fv[j]);
      h8[j] = (short)hu;
      l8[j] = (short)f2b(fv[j] - b2f(hu));
    }
    ah[c] = h8; al[c] = l8;
  }

  f32x4 acc[4];
#pragma unroll
  for (int n = 0; n < 4; ++n) acc[n] = (f32x4){0.f, 0.f, 0.f, 0.f};
#pragma unroll
  for (int n = 0; n < 4; ++n) {
    const int f = wid * 64 + n * 16 + l15;
    const ushort* brh = whh + (size_t)f * DK + 8 * g;
    const ushort* brl = whl + (size_t)f * DK + 8 * g;
#pragma unroll
    for (int c = 0; c < 2; ++c) {
      bf16x8 bh = ld8(brh + c * 32);
      bf16x8 bl = ld8(brl + c * 32);
      acc[n] = MFMA(ah[c], bh, acc[n]);
      acc[n] = MFMA(al[c], bh, acc[n]);
      acc[n] = MFMA(ah[c], bl, acc[n]);
    }
  }

#pragma unroll
  for (int n = 0; n < 4; ++n) {
    const int f = wid * 64 + n * 16 + l15;
#pragma unroll
    for (int r = 0; r < 4; ++r)
      out[(size_t)(row0 + 4 * g + r) * DM + f] = acc[n][r];
  }
}

extern "C" void kernel_launch(void* const* d_in, const int* in_sizes, int n_in,
                              void* d_out, int out_size, void* d_ws, size_t ws_size,
                              hipStream_t stream) {
  const float* q = (const float*)d_in[0];
  const float* k = (const float*)d_in[1];
  const float* v = (const float*)d_in[2];
  const float* Wq = (const float*)d_in[3];
  const float* Wk = (const float*)d_in[4];
  const float* Wv = (const float*)d_in[5];
  const float* Wh = (const float*)d_in[6];

  float* out = (float*)d_out;                  // [B,S,DM]
  float* attn_out = out + (size_t)B * S * DM;  // [B,S,H,S]

  const size_t n1 = (size_t)B * H * S * DK;  // 2,097,152
  ushort* qhi = (ushort*)d_ws;
  ushort* qlo = qhi + n1;
  ushort* khi = qlo + n1;
  ushort* klo = khi + n1;
  ushort* vT = klo + n1;                              // B*DK*S
  float* heads = (float*)(vT + (size_t)B * DK * S);   // [B,H,S,DK] fp32
  ushort* wqh = (ushort*)(heads + n1);                // 65536 each
  ushort* wql = wqh + (size_t)H * DK * DM;
  ushort* wkh = wql + (size_t)H * DK * DM;
  ushort* wkl = wkh + (size_t)H * DK * DM;
  ushort* wvh = wkl + (size_t)H * DK * DM;            // 16384 each
  ushort* wvl = wvh + (size_t)DK * DM;
  ushort* whh = wvl + (size_t)DK * DM;                // 16384 each
  ushort* whl = whh + (size_t)DM * DK;

  wsplit_kernel<<<832, 256, 0, stream>>>(Wq, Wk, Wv, Wh, wqh, wql, wkh, wkl,
                                         wvh, wvl, whh, whl);
  proj_qk2<<<1024, 256, 0, stream>>>(q, k, wqh, wql, wkh, wkl, qhi, qlo, khi, klo);
  proj_v<<<128, 256, 0, stream>>>(v, wvh, wvl, vT);
  attn_kernel<<<256, 512, 0, stream>>>(qhi, qlo, khi, klo, vT, attn_out, heads);
  out_mfma<<<512, 256, 0, stream>>>(heads, whh, whl, out);
}